// Round 1
// baseline (150.001 us; speedup 1.0000x reference)
//
#include <hip/hip_runtime.h>
#include <hip/hip_bf16.h>

#define BATCH 1024
#define NA 32
#define UD 64
#define HID 128

typedef short bf16x8 __attribute__((ext_vector_type(8)));
typedef float f32x4 __attribute__((ext_vector_type(4)));

static __device__ __forceinline__ short f2bf(float x) {
    union { __hip_bfloat16 b; short s; } u;
    u.b = __float2bfloat16(x);
    return u.s;
}

// One block per batch element. 512 threads = 8 waves.
// Phase A: hi = us@W1[:64] + b1, hj = us@W1[64:]  (32x128 each, fp32 in LDS)
// Phase B: per pair (i,j): x = relu(hi_i + hj_j) -> bf16, y = relu(x@W2+b2),
//          logit = y.W3 + b3, out = sigmoid(logit) + (i==j).
// LDS tiles XOR-swizzled at 16B granularity by (row&7) to avoid the 16-way
// bank conflict of 512B/128B row strides.
__global__ __launch_bounds__(512, 2)
void graph_learner_kernel(const float* __restrict__ us_g,
                          const float* __restrict__ W1,
                          const float* __restrict__ b1,
                          const float* __restrict__ W2,
                          const float* __restrict__ b2,
                          const float* __restrict__ W3,
                          const float* __restrict__ b3,
                          float* __restrict__ out)
{
    __shared__ short us_bf[NA * UD] __attribute__((aligned(16)));     // 4 KB bf16, swizzled
    __shared__ float hi_lds[NA * HID] __attribute__((aligned(16)));   // 16 KB f32, swizzled
    __shared__ float hj_lds[NA * HID] __attribute__((aligned(16)));   // 16 KB f32, swizzled

    const int b    = blockIdx.x;
    const int t    = threadIdx.x;
    const int w    = t >> 6;
    const int lane = t & 63;
    const int l15  = lane & 15;
    const int lq   = lane >> 4;

    // ---- stage unit_states[:, b, :] -> us_bf (bf16, chunk-swizzled)
    {
        int i  = t >> 4;           // agent 0..31
        int d0 = (t & 15) * 4;     // 0,4,...,60
        const float* src = us_g + ((size_t)i * BATCH + (size_t)b) * UD + d0;
        float4 v = *(const float4*)src;
        int c  = d0 >> 3;          // 16B chunk 0..7
        int hs = (d0 >> 2) & 1;    // half-chunk
        int idx = i * UD + (((c ^ (i & 7)) << 3) + (hs << 2));
        short4 s4;
        s4.x = f2bf(v.x); s4.y = f2bf(v.y); s4.z = f2bf(v.z); s4.w = f2bf(v.w);
        *(short4*)&us_bf[idx] = s4;
    }

    // ---- per-wave phase-A assignment: Mtile = w>>2 (agents 16*Mt..), nts {nt0,nt0+1}
    const int Mt  = w >> 2;
    const int nt0 = (w & 3) * 2;

    // W1 fragments: [n][0=hi half,1=hj half][ks]
    bf16x8 w1f[2][2][2];
    float  b1v[2];
    #pragma unroll
    for (int n = 0; n < 2; ++n) {
        int col = (nt0 + n) * 16 + l15;
        b1v[n] = b1[col];
        #pragma unroll
        for (int ks = 0; ks < 2; ++ks) {
            #pragma unroll
            for (int e = 0; e < 8; ++e) {
                int k = ks * 32 + lq * 8 + e;
                w1f[n][0][ks][e] = f2bf(W1[k * HID + col]);
                w1f[n][1][ks][e] = f2bf(W1[(UD + k) * HID + col]);
            }
        }
    }

    // W2 fragments (all 8 N-tiles x 4 K-steps, kept in registers) + b2/W3
    bf16x8 w2f[32];
    float  b2v[8], w3v[8];
    #pragma unroll
    for (int nt = 0; nt < 8; ++nt) {
        int col = nt * 16 + l15;
        b2v[nt] = b2[col];
        w3v[nt] = W3[col];
    }
    #pragma unroll
    for (int ks = 0; ks < 4; ++ks) {
        #pragma unroll
        for (int nt = 0; nt < 8; ++nt) {
            int col = nt * 16 + l15;
            int k0  = ks * 32 + lq * 8;
            #pragma unroll
            for (int e = 0; e < 8; ++e)
                w2f[ks * 8 + nt][e] = f2bf(W2[(k0 + e) * HID + col]);
        }
    }
    const float b3s = b3[0];

    __syncthreads();

    // ---- phase A: 8 MFMAs/wave
    {
        const f32x4 zf = {0.f, 0.f, 0.f, 0.f};
        bf16x8 af[2];
        #pragma unroll
        for (int ks = 0; ks < 2; ++ks) {
            int row = Mt * 16 + l15;
            int c   = ks * 4 + lq;
            af[ks] = *(const bf16x8*)&us_bf[row * UD + ((c ^ (row & 7)) << 3)];
        }
        f32x4 ahi[2] = {zf, zf}, ahj[2] = {zf, zf};
        #pragma unroll
        for (int ks = 0; ks < 2; ++ks) {
            #pragma unroll
            for (int n = 0; n < 2; ++n) {
                ahi[n] = __builtin_amdgcn_mfma_f32_16x16x32_bf16(af[ks], w1f[n][0][ks], ahi[n], 0, 0, 0);
                ahj[n] = __builtin_amdgcn_mfma_f32_16x16x32_bf16(af[ks], w1f[n][1][ks], ahj[n], 0, 0, 0);
            }
        }
        // write hi (+b1) / hj, swizzled
        #pragma unroll
        for (int n = 0; n < 2; ++n) {
            int col = (nt0 + n) * 16 + l15;
            #pragma unroll
            for (int r = 0; r < 4; ++r) {
                int rowi = Mt * 16 + lq * 4 + r;
                int idx  = rowi * HID + ((((col >> 2) ^ (rowi & 7)) << 2) + (col & 3));
                hi_lds[idx] = ahi[n][r] + b1v[n];
                hj_lds[idx] = ahj[n][r];
            }
        }
    }
    __syncthreads();

    // ---- phase B: wave w handles M-tiles w, w+8, ..., w+56 (16 pairs each)
    #pragma unroll 1
    for (int mt = w; mt < 64; mt += 8) {
        const int i   = mt >> 1;                 // fixed per tile
        const int j   = ((mt & 1) << 4) + l15;   // A-fragment row -> agent j
        const float* hir = &hi_lds[i * HID];
        const float* hjr = &hj_lds[j * HID];
        const int isz = i & 7, jsz = j & 7;

        const f32x4 zf = {0.f, 0.f, 0.f, 0.f};
        f32x4 acc[8];
        #pragma unroll
        for (int nt = 0; nt < 8; ++nt) acc[nt] = zf;

        #pragma unroll
        for (int ks = 0; ks < 4; ++ks) {
            int c0 = ks * 8 + lq * 2;
            f32x4 h0 = *(const f32x4*)&hir[((c0    ) ^ isz) << 2];
            f32x4 h1 = *(const f32x4*)&hir[((c0 + 1) ^ isz) << 2];
            f32x4 g0 = *(const f32x4*)&hjr[((c0    ) ^ jsz) << 2];
            f32x4 g1 = *(const f32x4*)&hjr[((c0 + 1) ^ jsz) << 2];
            bf16x8 a;
            #pragma unroll
            for (int e = 0; e < 4; ++e) {
                a[e]     = f2bf(fmaxf(h0[e] + g0[e], 0.f));
                a[e + 4] = f2bf(fmaxf(h1[e] + g1[e], 0.f));
            }
            #pragma unroll
            for (int nt = 0; nt < 8; ++nt)
                acc[nt] = __builtin_amdgcn_mfma_f32_16x16x32_bf16(a, w2f[ks * 8 + nt], acc[nt], 0, 0, 0);
        }

        // epilogue: y = relu(acc+b2); partial logit = y . W3 over this lane's 8 cols
        float p0r = 0.f, p1r = 0.f, p2r = 0.f, p3r = 0.f;
        #pragma unroll
        for (int nt = 0; nt < 8; ++nt) {
            p0r += fmaxf(acc[nt][0] + b2v[nt], 0.f) * w3v[nt];
            p1r += fmaxf(acc[nt][1] + b2v[nt], 0.f) * w3v[nt];
            p2r += fmaxf(acc[nt][2] + b2v[nt], 0.f) * w3v[nt];
            p3r += fmaxf(acc[nt][3] + b2v[nt], 0.f) * w3v[nt];
        }
        #pragma unroll
        for (int m = 1; m < 16; m <<= 1) {
            p0r += __shfl_xor(p0r, m);
            p1r += __shfl_xor(p1r, m);
            p2r += __shfl_xor(p2r, m);
            p3r += __shfl_xor(p3r, m);
        }
        if (l15 == 0) {
            int pbase = mt * 16 + lq * 4;   // pair index of r=0
            float4 o;
            {
                float x = p0r + b3s; int p = pbase + 0;
                o.x = 1.f / (1.f + __expf(-x)) + (((p >> 5) == (p & 31)) ? 1.f : 0.f);
            }
            {
                float x = p1r + b3s; int p = pbase + 1;
                o.y = 1.f / (1.f + __expf(-x)) + (((p >> 5) == (p & 31)) ? 1.f : 0.f);
            }
            {
                float x = p2r + b3s; int p = pbase + 2;
                o.z = 1.f / (1.f + __expf(-x)) + (((p >> 5) == (p & 31)) ? 1.f : 0.f);
            }
            {
                float x = p3r + b3s; int p = pbase + 3;
                o.w = 1.f / (1.f + __expf(-x)) + (((p >> 5) == (p & 31)) ? 1.f : 0.f);
            }
            *(float4*)&out[(size_t)b * (NA * NA) + pbase] = o;
        }
    }
}

extern "C" void kernel_launch(void* const* d_in, const int* in_sizes, int n_in,
                              void* d_out, int out_size, void* d_ws, size_t ws_size,
                              hipStream_t stream) {
    // inputs: 0=state (unused), 1=unit_states, 2=W1, 3=b1, 4=W2, 5=b2, 6=W3, 7=b3
    const float* us = (const float*)d_in[1];
    const float* W1 = (const float*)d_in[2];
    const float* b1 = (const float*)d_in[3];
    const float* W2 = (const float*)d_in[4];
    const float* b2 = (const float*)d_in[5];
    const float* W3 = (const float*)d_in[6];
    const float* b3 = (const float*)d_in[7];
    float* out = (float*)d_out;

    graph_learner_kernel<<<dim3(BATCH), dim3(512), 0, stream>>>(
        us, W1, b1, W2, b2, W3, b3, out);
}

// Round 2
// 136.193 us; speedup vs baseline: 1.1014x; 1.1014x over previous
//
#include <hip/hip_runtime.h>
#include <hip/hip_bf16.h>

#define BATCH 1024
#define NA 32
#define UD 64
#define HID 128

typedef short bf16x8 __attribute__((ext_vector_type(8)));
typedef float f32x4 __attribute__((ext_vector_type(4)));

static __device__ __forceinline__ short f2bf(float x) {
    union { __hip_bfloat16 b; short s; } u;
    u.b = __float2bfloat16(x);
    return u.s;
}

// ---------------------------------------------------------------------------
// Prep kernel: lay out W1/W2 as bf16 MFMA fragments in d_ws so the main
// kernel loads each fragment with one coalesced global_load_dwordx4.
// ws layout (shorts):
//   [unit 0..31 ]  W2 frag (unit = ks*8+nt, ks in 0..3)      : (unit*64+lane)*8
//   [unit 32..63]  W1 frag (u = h*16+ks*8+nt, ks in 0..1)    : ((32+u)*64+lane)*8
// Total 64 units * 64 lanes * 8 shorts = 64 KB.
// ---------------------------------------------------------------------------
__global__ void prep_weights(const float* __restrict__ W1,
                             const float* __restrict__ W2,
                             short* __restrict__ ws)
{
    int tid  = blockIdx.x * blockDim.x + threadIdx.x;  // 0..4095
    int unit = tid >> 6;
    int lane = tid & 63;
    int l15  = lane & 15;
    int lq   = lane >> 4;
    bf16x8 v;
    if (unit < 32) {
        int ks = unit >> 3, nt = unit & 7;             // ks 0..3
        int col = nt * 16 + l15;
        int k0  = ks * 32 + lq * 8;
        #pragma unroll
        for (int e = 0; e < 8; ++e)
            v[e] = f2bf(W2[(k0 + e) * HID + col]);
    } else {
        int u = unit - 32;                             // h*16 + ks*8 + nt
        int h = u >> 4, ks = (u >> 3) & 1, nt = u & 7;
        int col = nt * 16 + l15;
        int k0  = ks * 32 + lq * 8;
        #pragma unroll
        for (int e = 0; e < 8; ++e)
            v[e] = f2bf(W1[(h * UD + k0 + e) * HID + col]);
    }
    *(bf16x8*)&ws[(size_t)(unit * 64 + lane) * 8] = v;
}

// ---------------------------------------------------------------------------
// Main kernel. One block per batch element, 512 threads = 8 waves.
// Phase A: hi = us@W1[:64] + b1, hj = us@W1[64:]  (32x128 each, fp32 in LDS)
// Phase B: per pair (i,j): x = relu(hi_i + hj_j) -> bf16, y = relu(x@W2+b2),
//          logit = y.W3 + b3, out = sigmoid(logit) + (i==j).
// LDS tiles XOR-swizzled at 16B granularity by (row&7).
// FROM_WS: load weight fragments pre-laid-out from ws (fast path); the
// in-kernel build path is kept only as a fallback if ws_size is too small.
// ---------------------------------------------------------------------------
template <bool FROM_WS>
__global__ __launch_bounds__(512, 2)
void graph_learner_kernel(const float* __restrict__ us_g,
                          const float* __restrict__ W1,
                          const float* __restrict__ b1,
                          const float* __restrict__ W2,
                          const float* __restrict__ b2,
                          const float* __restrict__ W3,
                          const float* __restrict__ b3,
                          const short* __restrict__ ws,
                          float* __restrict__ out)
{
    __shared__ short us_bf[NA * UD] __attribute__((aligned(16)));     // 4 KB
    __shared__ float hi_lds[NA * HID] __attribute__((aligned(16)));   // 16 KB
    __shared__ float hj_lds[NA * HID] __attribute__((aligned(16)));   // 16 KB

    const int b    = blockIdx.x;
    const int t    = threadIdx.x;
    const int w    = t >> 6;
    const int lane = t & 63;
    const int l15  = lane & 15;
    const int lq   = lane >> 4;

    // ---- stage unit_states[:, b, :] -> us_bf (bf16, chunk-swizzled)
    {
        int i  = t >> 4;           // agent 0..31
        int d0 = (t & 15) * 4;     // 0,4,...,60
        const float* src = us_g + ((size_t)i * BATCH + (size_t)b) * UD + d0;
        float4 v = *(const float4*)src;
        int c  = d0 >> 3;
        int hs = (d0 >> 2) & 1;
        int idx = i * UD + (((c ^ (i & 7)) << 3) + (hs << 2));
        short4 s4;
        s4.x = f2bf(v.x); s4.y = f2bf(v.y); s4.z = f2bf(v.z); s4.w = f2bf(v.w);
        *(short4*)&us_bf[idx] = s4;
    }

    const int Mt  = w >> 2;
    const int nt0 = (w & 3) * 2;

    // ---- weight fragments
    bf16x8 w1f[2][2][2];   // [n][h][ks]
    float  b1v[2];
    bf16x8 w2f[32];
    float  b2v[8], w3v[8];

    #pragma unroll
    for (int n = 0; n < 2; ++n)
        b1v[n] = b1[(nt0 + n) * 16 + l15];
    #pragma unroll
    for (int nt = 0; nt < 8; ++nt) {
        int col = nt * 16 + l15;
        b2v[nt] = b2[col];
        w3v[nt] = W3[col];
    }
    const float b3s = b3[0];

    if (FROM_WS) {
        #pragma unroll
        for (int i = 0; i < 32; ++i)
            w2f[i] = *(const bf16x8*)&ws[(size_t)(i * 64 + lane) * 8];
        #pragma unroll
        for (int n = 0; n < 2; ++n)
            #pragma unroll
            for (int h = 0; h < 2; ++h)
                #pragma unroll
                for (int ks = 0; ks < 2; ++ks) {
                    int u = h * 16 + ks * 8 + (nt0 + n);
                    w1f[n][h][ks] = *(const bf16x8*)&ws[(size_t)((32 + u) * 64 + lane) * 8];
                }
    } else {
        #pragma unroll
        for (int n = 0; n < 2; ++n) {
            int col = (nt0 + n) * 16 + l15;
            #pragma unroll
            for (int ks = 0; ks < 2; ++ks)
                #pragma unroll
                for (int e = 0; e < 8; ++e) {
                    int k = ks * 32 + lq * 8 + e;
                    w1f[n][0][ks][e] = f2bf(W1[k * HID + col]);
                    w1f[n][1][ks][e] = f2bf(W1[(UD + k) * HID + col]);
                }
        }
        #pragma unroll
        for (int ks = 0; ks < 4; ++ks)
            #pragma unroll
            for (int nt = 0; nt < 8; ++nt) {
                int col = nt * 16 + l15;
                int k0  = ks * 32 + lq * 8;
                #pragma unroll
                for (int e = 0; e < 8; ++e)
                    w2f[ks * 8 + nt][e] = f2bf(W2[(k0 + e) * HID + col]);
            }
    }

    __syncthreads();

    // ---- phase A: 8 MFMAs/wave
    {
        const f32x4 zf = {0.f, 0.f, 0.f, 0.f};
        bf16x8 af[2];
        #pragma unroll
        for (int ks = 0; ks < 2; ++ks) {
            int row = Mt * 16 + l15;
            int c   = ks * 4 + lq;
            af[ks] = *(const bf16x8*)&us_bf[row * UD + ((c ^ (row & 7)) << 3)];
        }
        f32x4 ahi[2] = {zf, zf}, ahj[2] = {zf, zf};
        #pragma unroll
        for (int ks = 0; ks < 2; ++ks) {
            #pragma unroll
            for (int n = 0; n < 2; ++n) {
                ahi[n] = __builtin_amdgcn_mfma_f32_16x16x32_bf16(af[ks], w1f[n][0][ks], ahi[n], 0, 0, 0);
                ahj[n] = __builtin_amdgcn_mfma_f32_16x16x32_bf16(af[ks], w1f[n][1][ks], ahj[n], 0, 0, 0);
            }
        }
        #pragma unroll
        for (int n = 0; n < 2; ++n) {
            int col = (nt0 + n) * 16 + l15;
            #pragma unroll
            for (int r = 0; r < 4; ++r) {
                int rowi = Mt * 16 + lq * 4 + r;
                int idx  = rowi * HID + ((((col >> 2) ^ (rowi & 7)) << 2) + (col & 3));
                hi_lds[idx] = ahi[n][r] + b1v[n];
                hj_lds[idx] = ahj[n][r];
            }
        }
    }
    __syncthreads();

    // ---- phase B: wave w handles M-tiles w, w+8, ..., w+56 (16 pairs each)
    #pragma unroll 1
    for (int mt = w; mt < 64; mt += 8) {
        const int i   = mt >> 1;
        const int j   = ((mt & 1) << 4) + l15;
        const float* hir = &hi_lds[i * HID];
        const float* hjr = &hj_lds[j * HID];
        const int isz = i & 7, jsz = j & 7;

        const f32x4 zf = {0.f, 0.f, 0.f, 0.f};
        f32x4 acc[8];
        #pragma unroll
        for (int nt = 0; nt < 8; ++nt) acc[nt] = zf;

        #pragma unroll
        for (int ks = 0; ks < 4; ++ks) {
            int c0 = ks * 8 + lq * 2;
            f32x4 h0 = *(const f32x4*)&hir[((c0    ) ^ isz) << 2];
            f32x4 h1 = *(const f32x4*)&hir[((c0 + 1) ^ isz) << 2];
            f32x4 g0 = *(const f32x4*)&hjr[((c0    ) ^ jsz) << 2];
            f32x4 g1 = *(const f32x4*)&hjr[((c0 + 1) ^ jsz) << 2];
            bf16x8 a;
            #pragma unroll
            for (int e = 0; e < 4; ++e) {
                a[e]     = f2bf(fmaxf(h0[e] + g0[e], 0.f));
                a[e + 4] = f2bf(fmaxf(h1[e] + g1[e], 0.f));
            }
            #pragma unroll
            for (int nt = 0; nt < 8; ++nt)
                acc[nt] = __builtin_amdgcn_mfma_f32_16x16x32_bf16(a, w2f[ks * 8 + nt], acc[nt], 0, 0, 0);
        }

        float p0r = 0.f, p1r = 0.f, p2r = 0.f, p3r = 0.f;
        #pragma unroll
        for (int nt = 0; nt < 8; ++nt) {
            p0r += fmaxf(acc[nt][0] + b2v[nt], 0.f) * w3v[nt];
            p1r += fmaxf(acc[nt][1] + b2v[nt], 0.f) * w3v[nt];
            p2r += fmaxf(acc[nt][2] + b2v[nt], 0.f) * w3v[nt];
            p3r += fmaxf(acc[nt][3] + b2v[nt], 0.f) * w3v[nt];
        }
        #pragma unroll
        for (int m = 1; m < 16; m <<= 1) {
            p0r += __shfl_xor(p0r, m);
            p1r += __shfl_xor(p1r, m);
            p2r += __shfl_xor(p2r, m);
            p3r += __shfl_xor(p3r, m);
        }
        if (l15 == 0) {
            int pbase = mt * 16 + lq * 4;
            float4 o;
            {
                float x = p0r + b3s; int p = pbase + 0;
                o.x = 1.f / (1.f + __expf(-x)) + (((p >> 5) == (p & 31)) ? 1.f : 0.f);
            }
            {
                float x = p1r + b3s; int p = pbase + 1;
                o.y = 1.f / (1.f + __expf(-x)) + (((p >> 5) == (p & 31)) ? 1.f : 0.f);
            }
            {
                float x = p2r + b3s; int p = pbase + 2;
                o.z = 1.f / (1.f + __expf(-x)) + (((p >> 5) == (p & 31)) ? 1.f : 0.f);
            }
            {
                float x = p3r + b3s; int p = pbase + 3;
                o.w = 1.f / (1.f + __expf(-x)) + (((p >> 5) == (p & 31)) ? 1.f : 0.f);
            }
            *(float4*)&out[(size_t)b * (NA * NA) + pbase] = o;
        }
    }
}

extern "C" void kernel_launch(void* const* d_in, const int* in_sizes, int n_in,
                              void* d_out, int out_size, void* d_ws, size_t ws_size,
                              hipStream_t stream) {
    // inputs: 0=state (unused), 1=unit_states, 2=W1, 3=b1, 4=W2, 5=b2, 6=W3, 7=b3
    const float* us = (const float*)d_in[1];
    const float* W1 = (const float*)d_in[2];
    const float* b1 = (const float*)d_in[3];
    const float* W2 = (const float*)d_in[4];
    const float* b2 = (const float*)d_in[5];
    const float* W3 = (const float*)d_in[6];
    const float* b3 = (const float*)d_in[7];
    float* out = (float*)d_out;
    short* ws  = (short*)d_ws;

    const bool use_ws = (ws_size >= 64u * 64u * 8u * sizeof(short));
    if (use_ws) {
        prep_weights<<<dim3(16), dim3(256), 0, stream>>>(W1, W2, ws);
        graph_learner_kernel<true><<<dim3(BATCH), dim3(512), 0, stream>>>(
            us, W1, b1, W2, b2, W3, b3, ws, out);
    } else {
        graph_learner_kernel<false><<<dim3(BATCH), dim3(512), 0, stream>>>(
            us, W1, b1, W2, b2, W3, b3, ws, out);
    }
}

// Round 3
// 116.110 us; speedup vs baseline: 1.2919x; 1.1730x over previous
//
#include <hip/hip_runtime.h>
#include <hip/hip_bf16.h>

#define BATCH 1024
#define NA 32
#define UD 64
#define HID 128

typedef _Float16 f16x8 __attribute__((ext_vector_type(8)));
typedef float f32x4 __attribute__((ext_vector_type(4)));

// ---------------------------------------------------------------------------
// Prep kernel: W1/W2 -> f16 MFMA fragments in ws.
//   unit 0..31 : W2 frag, unit = ks*8+nt (ks 0..3)   lane holds W2[k0+e][nt*16+l15]
//   unit 32..63: W1 frag, u = h*16+ks*8+nt (ks 0..1) lane holds W1[h*64+k0+e][...]
// 64 units * 64 lanes * 8 halfs = 64 KB.
// ---------------------------------------------------------------------------
__global__ void prep_weights(const float* __restrict__ W1,
                             const float* __restrict__ W2,
                             _Float16* __restrict__ ws)
{
    int tid  = blockIdx.x * blockDim.x + threadIdx.x;  // 0..4095
    int unit = tid >> 6;
    int lane = tid & 63;
    int l15  = lane & 15;
    int lq   = lane >> 4;
    f16x8 v;
    if (unit < 32) {
        int ks = unit >> 3, nt = unit & 7;
        int col = nt * 16 + l15;
        int k0  = ks * 32 + lq * 8;
        #pragma unroll
        for (int e = 0; e < 8; ++e)
            v[e] = (_Float16)W2[(k0 + e) * HID + col];
    } else {
        int u = unit - 32;
        int h = u >> 4, ks = (u >> 3) & 1, nt = u & 7;
        int col = nt * 16 + l15;
        int k0  = ks * 32 + lq * 8;
        #pragma unroll
        for (int e = 0; e < 8; ++e)
            v[e] = (_Float16)W1[(h * UD + k0 + e) * HID + col];
    }
    *(f16x8*)&ws[(size_t)(unit * 64 + lane) * 8] = v;
}

// ---------------------------------------------------------------------------
// Main kernel: one block per batch element, 256 threads = 4 waves.
// Phase A: hi = us@W1[:64]+b1, hj = us@W1[64:]  -> f16 in LDS (XOR-swizzled).
// Phase B (swapped GEMM): per 16-pair tile, D[hidden][pair] =
//   mfma(W2frag, relu(hi_i + hj_j)) with C-init = b2; then per-lane
//   p = sum relu-free fmax(acc)*W3, 2 shuffles, sigmoid on all lanes, +eye.
// ---------------------------------------------------------------------------
template <bool FROM_WS>
__global__ __launch_bounds__(256, 2)
void graph_learner_kernel(const float* __restrict__ us_g,
                          const float* __restrict__ W1,
                          const float* __restrict__ b1,
                          const float* __restrict__ W2,
                          const float* __restrict__ b2,
                          const float* __restrict__ W3,
                          const float* __restrict__ b3,
                          const _Float16* __restrict__ ws,
                          float* __restrict__ out)
{
    __shared__ _Float16 us_f16[NA * UD]  __attribute__((aligned(16)));  // 4 KB
    __shared__ _Float16 hi_lds[NA * HID] __attribute__((aligned(16)));  // 8 KB
    __shared__ _Float16 hj_lds[NA * HID] __attribute__((aligned(16)));  // 8 KB

    const int b    = blockIdx.x;
    const int t    = threadIdx.x;
    const int w    = t >> 6;        // wave 0..3
    const int lane = t & 63;
    const int l15  = lane & 15;
    const int lq   = lane >> 4;

    // ---- stage unit_states[:, b, :] -> us_f16 (chunk-swizzled)
    {
        int i  = t >> 3;            // agent 0..31
        int c  = t & 7;             // 8-half chunk
        const float* src = us_g + ((size_t)i * BATCH + (size_t)b) * UD + c * 8;
        float4 va = *(const float4*)src;
        float4 vb = *(const float4*)(src + 4);
        f16x8 v8;
        v8[0] = (_Float16)va.x; v8[1] = (_Float16)va.y;
        v8[2] = (_Float16)va.z; v8[3] = (_Float16)va.w;
        v8[4] = (_Float16)vb.x; v8[5] = (_Float16)vb.y;
        v8[6] = (_Float16)vb.z; v8[7] = (_Float16)vb.w;
        *(f16x8*)&us_f16[i * UD + ((c ^ (i & 7)) << 3)] = v8;
    }

    // ---- small per-lane params
    f32x4 b2q[8], w3q[8];
    #pragma unroll
    for (int nt = 0; nt < 8; ++nt) {
        b2q[nt] = *(const f32x4*)&b2[nt * 16 + lq * 4];
        w3q[nt] = *(const f32x4*)&W3[nt * 16 + lq * 4];
    }
    const float b3s = b3[0];

    // ---- phase-A assignment: Mt = w>>1 (16 agent rows), n-half = w&1 (4 n-tiles)
    const int Mt = w >> 1;
    const int nh = w & 1;

    // w1f[n][h][ks]
    f16x8 w1f[4][2][2];
    float b1v[4];
    #pragma unroll
    for (int n = 0; n < 4; ++n) {
        int nt = nh * 4 + n;
        b1v[n] = b1[nt * 16 + l15];
        if (FROM_WS) {
            #pragma unroll
            for (int h = 0; h < 2; ++h)
                #pragma unroll
                for (int ks = 0; ks < 2; ++ks) {
                    int u = 32 + h * 16 + ks * 8 + nt;
                    w1f[n][h][ks] = *(const f16x8*)&ws[(size_t)(u * 64 + lane) * 8];
                }
        } else {
            int col = nt * 16 + l15;
            #pragma unroll
            for (int h = 0; h < 2; ++h)
                #pragma unroll
                for (int ks = 0; ks < 2; ++ks)
                    #pragma unroll
                    for (int e = 0; e < 8; ++e)
                        w1f[n][h][ks][e] = (_Float16)W1[(h * UD + ks * 32 + lq * 8 + e) * HID + col];
        }
    }

    __syncthreads();

    // ---- phase A: 16 MFMAs/wave; hi gets b1 via C-init
    {
        f16x8 af[2];
        #pragma unroll
        for (int ks = 0; ks < 2; ++ks) {
            int row = Mt * 16 + l15;
            int c   = ks * 4 + lq;
            af[ks] = *(const f16x8*)&us_f16[row * UD + ((c ^ (row & 7)) << 3)];
        }
        #pragma unroll
        for (int n = 0; n < 4; ++n) {
            int nt = nh * 4 + n;
            f32x4 ahi = {b1v[n], b1v[n], b1v[n], b1v[n]};
            f32x4 ahj = {0.f, 0.f, 0.f, 0.f};
            #pragma unroll
            for (int ks = 0; ks < 2; ++ks) {
                ahi = __builtin_amdgcn_mfma_f32_16x16x32_f16(af[ks], w1f[n][0][ks], ahi, 0, 0, 0);
                ahj = __builtin_amdgcn_mfma_f32_16x16x32_f16(af[ks], w1f[n][1][ks], ahj, 0, 0, 0);
            }
            #pragma unroll
            for (int r = 0; r < 4; ++r) {
                int row = Mt * 16 + lq * 4 + r;
                int col = nt * 16 + l15;
                int idx = row * HID + ((((col >> 3) ^ (row & 15)) << 3) + (col & 7));
                hi_lds[idx] = (_Float16)ahi[r];
                hj_lds[idx] = (_Float16)ahj[r];
            }
        }
    }

    // ---- W2 fragments (issued before the barrier so the drain hides latency)
    f16x8 w2f[32];
    if (FROM_WS) {
        #pragma unroll
        for (int q = 0; q < 32; ++q)
            w2f[q] = *(const f16x8*)&ws[(size_t)(q * 64 + lane) * 8];
    } else {
        #pragma unroll
        for (int ks = 0; ks < 4; ++ks)
            #pragma unroll
            for (int nt = 0; nt < 8; ++nt) {
                int col = nt * 16 + l15;
                int k0  = ks * 32 + lq * 8;
                #pragma unroll
                for (int e = 0; e < 8; ++e)
                    w2f[ks * 8 + nt][e] = (_Float16)W2[(k0 + e) * HID + col];
            }
    }

    __syncthreads();

    // pin w2f so the compiler cannot rematerialize the loads inside the loop
    #pragma unroll
    for (int q = 0; q < 32; q += 4)
        asm volatile("" : "+v"(w2f[q]), "+v"(w2f[q + 1]), "+v"(w2f[q + 2]), "+v"(w2f[q + 3]));

    // ---- phase B: wave w -> tiles mt = w, w+4, ..., w+60 (16 pairs each)
    #pragma unroll 1
    for (int tt = 0; tt < 16; ++tt) {
        const int mt = w + tt * 4;
        const int i  = mt >> 1;
        const int j  = ((mt & 1) << 4) + l15;
        const _Float16* hir = &hi_lds[i * HID];
        const _Float16* hjr = &hj_lds[j * HID];
        const int isz = i & 15, jsz = j & 15;

        f32x4 acc[8];
        #pragma unroll
        for (int nt = 0; nt < 8; ++nt) acc[nt] = b2q[nt];

        #pragma unroll
        for (int ks = 0; ks < 4; ++ks) {
            int c0 = ks * 4 + lq;
            f16x8 hi8 = *(const f16x8*)&hir[(c0 ^ isz) << 3];
            f16x8 hj8 = *(const f16x8*)&hjr[(c0 ^ jsz) << 3];
            f16x8 s   = hi8 + hj8;
            f16x8 z   = {};
            f16x8 xb  = __builtin_elementwise_max(s, z);
            #pragma unroll
            for (int nt = 0; nt < 8; ++nt)
                acc[nt] = __builtin_amdgcn_mfma_f32_16x16x32_f16(w2f[ks * 8 + nt], xb, acc[nt], 0, 0, 0);
        }

        // layer 3: per-lane partial over its 32 hidden values, then 2 shuffles
        float p = 0.f;
        #pragma unroll
        for (int nt = 0; nt < 8; ++nt) {
            p += fmaxf(acc[nt][0], 0.f) * w3q[nt][0];
            p += fmaxf(acc[nt][1], 0.f) * w3q[nt][1];
            p += fmaxf(acc[nt][2], 0.f) * w3q[nt][2];
            p += fmaxf(acc[nt][3], 0.f) * w3q[nt][3];
        }
        p += __shfl_xor(p, 16);
        p += __shfl_xor(p, 32);

        float x  = p + b3s;
        float sg = 1.f / (1.f + __expf(-x));
        int   pi = mt * 16 + l15;
        sg += ((pi >> 5) == (pi & 31)) ? 1.f : 0.f;
        if (lane < 16)
            out[(size_t)b * (NA * NA) + pi] = sg;
    }
}

extern "C" void kernel_launch(void* const* d_in, const int* in_sizes, int n_in,
                              void* d_out, int out_size, void* d_ws, size_t ws_size,
                              hipStream_t stream) {
    // inputs: 0=state (unused), 1=unit_states, 2=W1, 3=b1, 4=W2, 5=b2, 6=W3, 7=b3
    const float* us = (const float*)d_in[1];
    const float* W1 = (const float*)d_in[2];
    const float* b1 = (const float*)d_in[3];
    const float* W2 = (const float*)d_in[4];
    const float* b2 = (const float*)d_in[5];
    const float* W3 = (const float*)d_in[6];
    const float* b3 = (const float*)d_in[7];
    float* out = (float*)d_out;
    _Float16* ws = (_Float16*)d_ws;

    const bool use_ws = (ws_size >= 64u * 64u * 8u * sizeof(_Float16));
    if (use_ws) {
        prep_weights<<<dim3(16), dim3(256), 0, stream>>>(W1, W2, ws);
        graph_learner_kernel<true><<<dim3(BATCH), dim3(256), 0, stream>>>(
            us, W1, b1, W2, b2, W3, b3, ws, out);
    } else {
        graph_learner_kernel<false><<<dim3(BATCH), dim3(256), 0, stream>>>(
            us, W1, b1, W2, b2, W3, b3, ws, out);
    }
}